// Round 1
// baseline (645.754 us; speedup 1.0000x reference)
//
#include <hip/hip_runtime.h>
#include <cmath>

#define NB 16384   // batch
#define NT 32      // time steps
#define NI 27      // input features
#define NH 32      // hidden
#define NG 26      // fc outputs / guessed features
#define NWAVES 1024  // 256 blocks * 4 waves; each wave handles NB/NWAVES = 16 batch elems

static __device__ __forceinline__ float bcastf(float v, int l) {
    // broadcast lane l's value to all lanes (SGPR) — l is compile-time in unrolled loops
    return __int_as_float(__builtin_amdgcn_readlane(__float_as_int(v), l));
}

__global__ __launch_bounds__(256, 1)
void lstm_fused(const float* __restrict__ X,    // [B,T,I] flat; consumed as [T,B,I] (raw reshape)
                const float* __restrict__ Gu,   // guessed [B,26]
                const float* __restrict__ H0, const float* __restrict__ C0,
                const float* __restrict__ Wih0, const float* __restrict__ Whh0,
                const float* __restrict__ bih0, const float* __restrict__ bhh0,
                const float* __restrict__ Wih1, const float* __restrict__ Whh1,
                const float* __restrict__ bih1, const float* __restrict__ bhh1,
                const float* __restrict__ Wfc, const float* __restrict__ bfc,
                float* __restrict__ out)
{
    const int lane = threadIdx.x & 63;
    const int gw   = blockIdx.x * (blockDim.x >> 6) + (threadIdx.x >> 6);
    const int rA   = lane;       // rows 0..63  : i (lane<32) / f (lane>=32)
    const int rB   = lane + 64;  // rows 64..127: g (lane<32) / o (lane>=32)
    const bool lo  = lane < NH;
    const int hl   = lane & (NH - 1);

    // ---- persistent per-lane weight rows (registers) ----
    float wA0[NI + NH], wB0[NI + NH], wA1[2 * NH], wB1[2 * NH];
#pragma unroll
    for (int k = 0; k < NI; ++k) { wA0[k] = Wih0[rA * NI + k]; wB0[k] = Wih0[rB * NI + k]; }
#pragma unroll
    for (int j = 0; j < NH; ++j) { wA0[NI + j] = Whh0[rA * NH + j]; wB0[NI + j] = Whh0[rB * NH + j]; }
#pragma unroll
    for (int j = 0; j < NH; ++j) { wA1[j] = Wih1[rA * NH + j]; wB1[j] = Wih1[rB * NH + j]; }
#pragma unroll
    for (int j = 0; j < NH; ++j) { wA1[NH + j] = Whh1[rA * NH + j]; wB1[NH + j] = Whh1[rB * NH + j]; }
    const float bA0 = bih0[rA] + bhh0[rA];
    const float bB0 = bih0[rB] + bhh0[rB];
    const float bA1 = bih1[rA] + bhh1[rA];
    const float bB1 = bih1[rB] + bhh1[rB];

#pragma unroll 1
    for (int b = gw; b < NB; b += NWAVES) {
        const int bs = __builtin_amdgcn_readfirstlane(b);

        // state: lanes<32 hold canonical h/c for hidden unit hl (upper lanes mirror garbage)
        float h1 = H0[(size_t)bs * NH + hl];
        float c1 = C0[(size_t)bs * NH + hl];
        float h2 = h1, c2 = c1, hsum = 0.0f;  // init aliases h0/c0 for both layers

        float u1[NH], u2[NH];  // wave-uniform broadcast copies of h1 / h2
#pragma unroll
        for (int j = 0; j < NH; ++j) { u1[j] = bcastf(h1, j); u2[j] = u1[j]; }

        // prefetch x for t=0 (uniform address -> scalar loads)
        float xn[NI];
        {
            const float* xp = X + (size_t)bs * NI;
#pragma unroll
            for (int k = 0; k < NI; ++k) xn[k] = xp[k];
        }

#pragma unroll 1
        for (int t = 0; t < NT; ++t) {
            float xv[NI];
#pragma unroll
            for (int k = 0; k < NI; ++k) xv[k] = xn[k];
            if (t + 1 < NT) {  // prefetch next step's x; consumed next iteration
                const float* xp = X + ((size_t)(t + 1) * NB + bs) * NI;
#pragma unroll
                for (int k = 0; k < NI; ++k) xn[k] = xp[k];
            }

            // ---------- layer 0: gates = x@Wih0^T + h1@Whh0^T + b ----------
            float aA = bA0, aB = bB0;
#pragma unroll
            for (int k = 0; k < NI; ++k) { aA = fmaf(xv[k], wA0[k], aA); aB = fmaf(xv[k], wB0[k], aB); }
#pragma unroll
            for (int j = 0; j < NH; ++j) { aA = fmaf(u1[j], wA0[NI + j], aA); aB = fmaf(u1[j], wB0[NI + j], aB); }
            // activations: rowA -> sigmoid (i or f); rowB -> tanh (g) on lo, sigmoid (o) on hi
            float sA   = 1.0f / (1.0f + __expf(-aA));
            float eB   = __expf(lo ? -2.0f * aB : -aB);
            float rBv  = 1.0f / (1.0f + eB);
            float actB = lo ? (2.0f * rBv - 1.0f) : rBv;
            float send1 = lo ? sA * actB : sA;        // lo: p = i*g ; hi: f
            float fx = __shfl_xor(send1, 32, 64);     // lo receives f
            float ox = __shfl_xor(actB, 32, 64);      // lo receives o
            c1 = fmaf(fx, c1, send1);                 // c = f*c + i*g   (valid on lo)
            float e2 = __expf(-2.0f * c1);
            h1 = ox * (2.0f / (1.0f + e2) - 1.0f);    // h = o*tanh(c)   (valid on lo)
#pragma unroll
            for (int j = 0; j < NH; ++j) u1[j] = bcastf(h1, j);

            // ---------- layer 1: gates = h1@Wih1^T + h2@Whh1^T + b ----------
            aA = bA1; aB = bB1;
#pragma unroll
            for (int j = 0; j < NH; ++j) { aA = fmaf(u1[j], wA1[j], aA); aB = fmaf(u1[j], wB1[j], aB); }
#pragma unroll
            for (int j = 0; j < NH; ++j) { aA = fmaf(u2[j], wA1[NH + j], aA); aB = fmaf(u2[j], wB1[NH + j], aB); }
            sA   = 1.0f / (1.0f + __expf(-aA));
            eB   = __expf(lo ? -2.0f * aB : -aB);
            rBv  = 1.0f / (1.0f + eB);
            actB = lo ? (2.0f * rBv - 1.0f) : rBv;
            send1 = lo ? sA * actB : sA;
            fx = __shfl_xor(send1, 32, 64);
            ox = __shfl_xor(actB, 32, 64);
            c2 = fmaf(fx, c2, send1);
            e2 = __expf(-2.0f * c2);
            h2 = ox * (2.0f / (1.0f + e2) - 1.0f);
            hsum += h2;                                // valid on lo lanes
#pragma unroll
            for (int j = 0; j < NH; ++j) u2[j] = bcastf(h2, j);
        }

        // ---------- fc head: logits = [hsum/T, guessed] @ Wfc^T + bfc ----------
        float uh[NH];
#pragma unroll
        for (int j = 0; j < NH; ++j) uh[j] = bcastf(hsum, j) * (1.0f / NT);
        if (lane < NG) {
            const float* wr = Wfc + lane * (NH + NG);
            const float* gp = Gu + (size_t)bs * NG;   // uniform address -> scalar loads
            float acc = bfc[lane];
#pragma unroll
            for (int j = 0; j < NH; ++j) acc = fmaf(uh[j], wr[j], acc);
#pragma unroll
            for (int k = 0; k < NG; ++k) acc = fmaf(gp[k], wr[NH + k], acc);
            out[(size_t)bs * NG + lane] = acc;
            out[(size_t)NB * NG + (size_t)bs * NG + lane] = 1.0f / (1.0f + __expf(-acc));
        }
    }
}

extern "C" void kernel_launch(void* const* d_in, const int* in_sizes, int n_in,
                              void* d_out, int out_size, void* d_ws, size_t ws_size,
                              hipStream_t stream) {
    const float* X    = (const float*)d_in[0];
    const float* Gu   = (const float*)d_in[1];
    const float* H0   = (const float*)d_in[2];
    const float* C0   = (const float*)d_in[3];
    const float* Wih0 = (const float*)d_in[4];
    const float* Whh0 = (const float*)d_in[5];
    const float* bih0 = (const float*)d_in[6];
    const float* bhh0 = (const float*)d_in[7];
    const float* Wih1 = (const float*)d_in[8];
    const float* Whh1 = (const float*)d_in[9];
    const float* bih1 = (const float*)d_in[10];
    const float* bhh1 = (const float*)d_in[11];
    const float* Wfc  = (const float*)d_in[12];
    const float* bfc  = (const float*)d_in[13];
    float* out = (float*)d_out;

    dim3 grid(256), block(256);  // 1024 waves, 16 batch elems per wave
    hipLaunchKernelGGL(lstm_fused, grid, block, 0, stream,
                       X, Gu, H0, C0, Wih0, Whh0, bih0, bhh0,
                       Wih1, Whh1, bih1, bhh1, Wfc, bfc, out);
}

// Round 4
// 77.472 us; speedup vs baseline: 8.3353x; 8.3353x over previous
//
#include <hip/hip_runtime.h>
#include <hip/hip_bf16.h>

#define NB 16384
#define NT 32
#define NI 27
#define NH 32
#define NG 26

typedef __attribute__((ext_vector_type(8))) short bf16x8;
typedef __attribute__((ext_vector_type(4))) float f32x4;
typedef __attribute__((ext_vector_type(4))) int   i32x4;

#define MFMA(a, b, c) __builtin_amdgcn_mfma_f32_16x16x32_bf16((a), (b), (c), 0, 0, 0)

static __device__ __forceinline__ int pack2(float lo, float hi) {
    unsigned short a = __builtin_bit_cast(unsigned short, __float2bfloat16(lo));
    unsigned short b = __builtin_bit_cast(unsigned short, __float2bfloat16(hi));
    return (int)(((unsigned)b << 16) | (unsigned)a);
}

static __device__ __forceinline__ float sigm(float x) {
    return __builtin_amdgcn_rcpf(1.0f + __expf(-x));
}
static __device__ __forceinline__ float tanh_(float x) {
    return 2.0f * __builtin_amdgcn_rcpf(1.0f + __expf(-2.0f * x)) - 1.0f;
}

// Load an MFMA A-fragment (lane: row = bl, k = k0..k0+7) from row-major W[nrows][rowlen],
// zero-padded outside. One-time setup cost; guarded scalar loads for simplicity/safety.
static __device__ __forceinline__ bf16x8 load_wfrag(const float* __restrict__ W,
                                                    int rowlen, int nrows, int row, int k0) {
    int w[4];
#pragma unroll
    for (int q = 0; q < 4; ++q) {
        int k = k0 + 2 * q;
        float lo = (row < nrows && k     < rowlen) ? W[row * rowlen + k]     : 0.0f;
        float hi = (row < nrows && k + 1 < rowlen) ? W[row * rowlen + k + 1] : 0.0f;
        w[q] = pack2(lo, hi);
    }
    i32x4 v = { w[0], w[1], w[2], w[3] };
    return __builtin_bit_cast(bf16x8, v);
}

// Redistribute h_new (lane-local activations: hn[r][mh] = h[hidden 16*mh + 4*g4 + r] of
// batch bl) into the MFMA B-fragment layout (lane needs k = 8*g4 + j for batch bl).
// Pure in-wave: 8x ds_bpermute within the 4-lane group {bl, bl+16, bl+32, bl+48}.
static __device__ __forceinline__ bf16x8 redist(const float hn[4][2], int a0, int a1, bool mhi) {
    int w00 = pack2(hn[0][0], hn[1][0]);  // m=0, p=0: hidden {4g4+0, 4g4+1}
    int w01 = pack2(hn[2][0], hn[3][0]);  // m=0, p=1: hidden {4g4+2, 4g4+3}
    int w10 = pack2(hn[0][1], hn[1][1]);  // m=1, p=0: hidden {16+4g4+0, +1}
    int w11 = pack2(hn[2][1], hn[3][1]);  // m=1, p=1
    int q0lo = __builtin_amdgcn_ds_bpermute(a0, w00), q0hi = __builtin_amdgcn_ds_bpermute(a0, w10);
    int q1lo = __builtin_amdgcn_ds_bpermute(a0, w01), q1hi = __builtin_amdgcn_ds_bpermute(a0, w11);
    int q2lo = __builtin_amdgcn_ds_bpermute(a1, w00), q2hi = __builtin_amdgcn_ds_bpermute(a1, w10);
    int q3lo = __builtin_amdgcn_ds_bpermute(a1, w01), q3hi = __builtin_amdgcn_ds_bpermute(a1, w11);
    i32x4 v = { mhi ? q0hi : q0lo, mhi ? q1hi : q1lo, mhi ? q2hi : q2lo, mhi ? q3hi : q3lo };
    return __builtin_bit_cast(bf16x8, v);
}

__global__ __launch_bounds__(256, 1)
void lstm_mfma(const float* __restrict__ X,   // [B,T,I] flat, consumed as [T,B,I]
               const float* __restrict__ Gu,  // [B,26]
               const float* __restrict__ H0, const float* __restrict__ C0,
               const float* __restrict__ Wih0, const float* __restrict__ Whh0,
               const float* __restrict__ bih0, const float* __restrict__ bhh0,
               const float* __restrict__ Wih1, const float* __restrict__ Whh1,
               const float* __restrict__ bih1, const float* __restrict__ bhh1,
               const float* __restrict__ Wfc, const float* __restrict__ bfc,
               float* __restrict__ out)
{
    const int lane = threadIdx.x & 63;
    const int bl   = lane & 15;        // batch slot within wave (MFMA col)
    const int g4   = lane >> 4;        // 4-lane group id
    const int k0   = 8 * g4;           // K-offset this lane supplies to A/B frags
    const int wid  = blockIdx.x * (blockDim.x >> 6) + (threadIdx.x >> 6);
    const int batch = wid * 16 + bl;
    const bool mhi = (g4 >> 1) != 0;
    const int a0 = 4 * (bl + 16 * (2 * (g4 & 1)));  // bpermute byte addrs (src lanes)
    const int a1 = a0 + 64;

    // ---------- persistent weight A-fragments + bias C-init (registers) ----------
    bf16x8 A0x[8], A0h[8], A1i[8], A1h[8];
    f32x4  b0[8], b1[8];
#pragma unroll
    for (int m = 0; m < 8; ++m) {
        A0x[m] = load_wfrag(Wih0, NI, 4 * NH, 16 * m + bl, k0);
        A0h[m] = load_wfrag(Whh0, NH, 4 * NH, 16 * m + bl, k0);
        A1i[m] = load_wfrag(Wih1, NH, 4 * NH, 16 * m + bl, k0);
        A1h[m] = load_wfrag(Whh1, NH, 4 * NH, 16 * m + bl, k0);
#pragma unroll
        for (int r = 0; r < 4; ++r) {
            int gr = 16 * m + 4 * g4 + r;  // C-layout row = gate index
            b0[m][r] = bih0[gr] + bhh0[gr];
            b1[m][r] = bih1[gr] + bhh1[gr];
        }
    }
    bf16x8 Afc0[2], Afc1[2];
#pragma unroll
    for (int m2 = 0; m2 < 2; ++m2) {
        Afc0[m2] = load_wfrag(Wfc, NH + NG, NG, 16 * m2 + bl, k0);       // hsum/T part
        Afc1[m2] = load_wfrag(Wfc, NH + NG, NG, 16 * m2 + bl, NH + k0);  // guessed part
    }

    // ---------- state init (init aliases h0/c0 for both layers) ----------
    const float* h0p = H0 + (size_t)batch * NH;
    const float* c0p = C0 + (size_t)batch * NH;
    int hw[4];
#pragma unroll
    for (int q = 0; q < 4; ++q) hw[q] = pack2(h0p[k0 + 2 * q], h0p[k0 + 2 * q + 1]);
    i32x4 hv = { hw[0], hw[1], hw[2], hw[3] };
    bf16x8 h1f = __builtin_bit_cast(bf16x8, hv);
    bf16x8 h2f = h1f;
    float c1[4][2], c2[4][2], hsum[4][2];
#pragma unroll
    for (int mh = 0; mh < 2; ++mh)
#pragma unroll
        for (int r = 0; r < 4; ++r) {
            float c = c0p[16 * mh + 4 * g4 + r];
            c1[r][mh] = c; c2[r][mh] = c; hsum[r][mh] = 0.0f;
        }

    // x prefetch (t=0); lane supplies x[batch][k0..k0+7], zero-padded past NI
    float xn[8];
    {
        const float* xp = X + ((size_t)0 * NB + batch) * NI;
#pragma unroll
        for (int j = 0; j < 8; ++j) { int k = k0 + j; xn[j] = (k < NI) ? xp[k] : 0.0f; }
    }

#pragma unroll 1
    for (int t = 0; t < NT; ++t) {
        // pack current x frag, then prefetch next t
        int xw[4];
#pragma unroll
        for (int q = 0; q < 4; ++q) xw[q] = pack2(xn[2 * q], xn[2 * q + 1]);
        i32x4 xv = { xw[0], xw[1], xw[2], xw[3] };
        bf16x8 xf = __builtin_bit_cast(bf16x8, xv);
        if (t + 1 < NT) {
            const float* xp = X + ((size_t)(t + 1) * NB + batch) * NI;
#pragma unroll
            for (int j = 0; j < 8; ++j) { int k = k0 + j; xn[j] = (k < NI) ? xp[k] : 0.0f; }
        }

        f32x4 g[8];
        // ---------- layer 0: gates^T = Wih0*x^T + Whh0*h1^T + b ----------
#pragma unroll
        for (int m = 0; m < 8; ++m) g[m] = MFMA(A0x[m], xf, b0[m]);
#pragma unroll
        for (int m = 0; m < 8; ++m) g[m] = MFMA(A0h[m], h1f, g[m]);
        // lane owns i,f,g,o for hidden {16*mh + 4*g4 + r} of batch bl
        float hn1[4][2];
#pragma unroll
        for (int mh = 0; mh < 2; ++mh)
#pragma unroll
            for (int r = 0; r < 4; ++r) {
                float iv = sigm(g[0 + mh][r]);
                float fv = sigm(g[2 + mh][r]);
                float gv = tanh_(g[4 + mh][r]);
                float ov = sigm(g[6 + mh][r]);
                float c  = fmaf(fv, c1[r][mh], iv * gv);
                c1[r][mh] = c;
                hn1[r][mh] = ov * tanh_(c);
            }
        h1f = redist(hn1, a0, a1, mhi);

        // ---------- layer 1: gates^T = Wih1*h1^T + Whh1*h2^T + b ----------
#pragma unroll
        for (int m = 0; m < 8; ++m) g[m] = MFMA(A1i[m], h1f, b1[m]);
#pragma unroll
        for (int m = 0; m < 8; ++m) g[m] = MFMA(A1h[m], h2f, g[m]);
        float hn2[4][2];
#pragma unroll
        for (int mh = 0; mh < 2; ++mh)
#pragma unroll
            for (int r = 0; r < 4; ++r) {
                float iv = sigm(g[0 + mh][r]);
                float fv = sigm(g[2 + mh][r]);
                float gv = tanh_(g[4 + mh][r]);
                float ov = sigm(g[6 + mh][r]);
                float c  = fmaf(fv, c2[r][mh], iv * gv);
                c2[r][mh] = c;
                float h = ov * tanh_(c);
                hn2[r][mh] = h;
                hsum[r][mh] += h;
            }
        h2f = redist(hn2, a0, a1, mhi);
    }

    // ---------- fc head: logits^T = Wfc[:, :32]*(hsum/T)^T + Wfc[:, 32:]*Gu^T + bfc ----------
    float hs[4][2];
#pragma unroll
    for (int mh = 0; mh < 2; ++mh)
#pragma unroll
        for (int r = 0; r < 4; ++r) hs[r][mh] = hsum[r][mh] * (1.0f / NT);
    bf16x8 hsf = redist(hs, a0, a1, mhi);

    int gw[4];
    {
        const float* gp = Gu + (size_t)batch * NG;
#pragma unroll
        for (int q = 0; q < 4; ++q) {
            int k = k0 + 2 * q;
            float lo = (k     < NG) ? gp[k]     : 0.0f;
            float hi = (k + 1 < NG) ? gp[k + 1] : 0.0f;
            gw[q] = pack2(lo, hi);
        }
    }
    i32x4 gv_ = { gw[0], gw[1], gw[2], gw[3] };
    bf16x8 guf = __builtin_bit_cast(bf16x8, gv_);

    f32x4 zero4 = { 0.0f, 0.0f, 0.0f, 0.0f };
    f32x4 L[2];
#pragma unroll
    for (int m2 = 0; m2 < 2; ++m2) L[m2] = MFMA(Afc0[m2], hsf, zero4);
#pragma unroll
    for (int m2 = 0; m2 < 2; ++m2) L[m2] = MFMA(Afc1[m2], guf, L[m2]);

#pragma unroll
    for (int m2 = 0; m2 < 2; ++m2)
#pragma unroll
        for (int r = 0; r < 4; ++r) {
            int row = 16 * m2 + 4 * g4 + r;
            if (row < NG) {
                float v = L[m2][r] + bfc[row];
                out[(size_t)batch * NG + row] = v;
                out[(size_t)NB * NG + (size_t)batch * NG + row] = sigm(v);
            }
        }
}

extern "C" void kernel_launch(void* const* d_in, const int* in_sizes, int n_in,
                              void* d_out, int out_size, void* d_ws, size_t ws_size,
                              hipStream_t stream) {
    const float* X    = (const float*)d_in[0];
    const float* Gu   = (const float*)d_in[1];
    const float* H0   = (const float*)d_in[2];
    const float* C0   = (const float*)d_in[3];
    const float* Wih0 = (const float*)d_in[4];
    const float* Whh0 = (const float*)d_in[5];
    const float* bih0 = (const float*)d_in[6];
    const float* bhh0 = (const float*)d_in[7];
    const float* Wih1 = (const float*)d_in[8];
    const float* Whh1 = (const float*)d_in[9];
    const float* bih1 = (const float*)d_in[10];
    const float* bhh1 = (const float*)d_in[11];
    const float* Wfc  = (const float*)d_in[12];
    const float* bfc  = (const float*)d_in[13];
    float* out = (float*)d_out;

    dim3 grid(NB / 16 / 4), block(256);  // 1024 waves, 16 batch rows per wave
    hipLaunchKernelGGL(lstm_mfma, grid, block, 0, stream,
                       X, Gu, H0, C0, Wih0, Whh0, bih0, bhh0,
                       Wih1, Whh1, bih1, bhh1, Wfc, bfc, out);
}